// Round 3
// baseline (145.011 us; speedup 1.0000x reference)
//
#include <hip/hip_runtime.h>

typedef float f32x4 __attribute__((ext_vector_type(4)));
typedef __bf16 bf16x8 __attribute__((ext_vector_type(8)));

#define SPAT 65536   // t*h*w
#define CH   128
#define NE   8

// LDS layout (bytes)
#define XS_OFF   0        // 65536: X tile [256 tok][128 ch] bf16 swizzled; aliased as H1 after xb preload
#define WA_OFF   65536    // 32768: W1[e] bf16 image
#define WB_OFF   98304    // 32768: W2[e] bf16 image
#define PL_OFF   65536    // 32768: gating partials f32[4 part][8 e][256 tok]  (aliases WA, prologue only)
#define SEL_OFF  131072   // 1024 : sel u32[256]
#define Q_OFF    132096   // 2048 : q f32[256][2]
#define CB_OFF   134144   // 4096 : combine bf16[256][8]
#define B1_OFF   138240   // 4096 : b1 f32[8][128]
#define B2T_OFF  142336   // 2048 : b2^T bf16[128][8]
#define AL_OFF   144384   // 32   : alpha f32[8]
#define LDS_BYTES 144416

static __device__ __forceinline__ unsigned short f2b(float f) {
    unsigned u = __builtin_bit_cast(unsigned, f);
    unsigned r = u + 0x7FFFu + ((u >> 16) & 1u);
    return (unsigned short)(r >> 16);
}
static __device__ __forceinline__ unsigned pk2(float a, float b) {
    return (unsigned)f2b(a) | ((unsigned)f2b(b) << 16);
}

typedef const __attribute__((address_space(1))) void* as1cp;
typedef __attribute__((address_space(3))) void* as3p;
static __device__ __forceinline__ void gload16(const void* g, void* l) {
    __builtin_amdgcn_global_load_lds((as1cp)g, (as3p)l, 16, 0, 0);
}

// Pre-convert W1/W2 fp32 -> bf16 images in ws, in swizzled LDS byte order:
// image = ws + mat*262144 + e*32768 + o*256 + ((g ^ (o&7))*16), granule g = 8 ch.
__global__ void conv_w(const float* __restrict__ W1, const float* __restrict__ W2,
                       unsigned char* __restrict__ wimg) {
    const int gid = blockIdx.x * 256 + threadIdx.x;   // 32768 granules
    const int mat = gid >> 14;
    const int e   = (gid >> 11) & 7;
    const int o   = (gid >> 4) & 127;
    const int g   = gid & 15;
    const float* s = (mat ? W2 : W1) + (e * 16384 + o * 128 + g * 8);
    uint4 p;
    p.x = pk2(s[0], s[1]); p.y = pk2(s[2], s[3]);
    p.z = pk2(s[4], s[5]); p.w = pk2(s[6], s[7]);
    *(uint4*)(wimg + mat * 262144 + e * 32768 + o * 256 + ((g ^ (o & 7)) * 16)) = p;
}

__global__ __launch_bounds__(1024, 4)
void moe_main(const float* __restrict__ x,  const float* __restrict__ gw,
              const float* __restrict__ gb, const float* __restrict__ b1,
              const float* __restrict__ alpha, const float* __restrict__ b2,
              const unsigned char* __restrict__ wimg, float* __restrict__ out)
{
    __shared__ __align__(16) unsigned char smem[LDS_BYTES];
    const int t = threadIdx.x, lane = t & 63, w = t >> 6, blk = blockIdx.x;
    const size_t xbase = (size_t)(blk >> 8) * (size_t)(CH * SPAT) + (size_t)((blk & 255) << 8);

    // stage small params (disjoint regions, before S1)
    if (t < 256) ((f32x4*)(smem + B1_OFF))[t] = ((const f32x4*)b1)[t];
    else if (t >= 256 && t < 384) {
        const int j = t - 256;
        uint4 p;
        p.x = pk2(b2[0 * 128 + j], b2[1 * 128 + j]);
        p.y = pk2(b2[2 * 128 + j], b2[3 * 128 + j]);
        p.z = pk2(b2[4 * 128 + j], b2[5 * 128 + j]);
        p.w = pk2(b2[6 * 128 + j], b2[7 * 128 + j]);
        *(uint4*)(smem + B2T_OFF + j * 16) = p;
    } else if (t >= 384 && t < 392) {
        ((float*)(smem + AL_OFF))[t - 384] = alpha[t - 384];
    }

    // ---- stage X (fp32->bf16, swizzled) + fp32 gating partials (4 parts x 32ch) ----
    {
        const int m = t & 255, p = t >> 8;     // token, channel-part
        f32x4 plo = {0.f,0.f,0.f,0.f}, phi = {0.f,0.f,0.f,0.f};
        #pragma unroll
        for (int cc = 0; cc < 4; ++cc) {
            const int c0 = p * 32 + cc * 8;
            float v[8];
            #pragma unroll
            for (int j = 0; j < 8; ++j) v[j] = x[xbase + (size_t)(c0 + j) * SPAT + m];
            #pragma unroll
            for (int j = 0; j < 8; ++j) {
                const f32x4 g0 = *(const f32x4*)(gw + (c0 + j) * NE);
                const f32x4 g1 = *(const f32x4*)(gw + (c0 + j) * NE + 4);
                plo += v[j] * g0; phi += v[j] * g1;
            }
            uint4 pkv;
            pkv.x = pk2(v[0], v[1]); pkv.y = pk2(v[2], v[3]);
            pkv.z = pk2(v[4], v[5]); pkv.w = pk2(v[6], v[7]);
            const int g = p * 4 + cc;
            *(uint4*)(smem + XS_OFF + m * 256 + ((g ^ (m & 7)) * 16)) = pkv;
        }
        // PL[part][e][tok] — stride-1 in tok => conflict-free
        float* pl = (float*)(smem + PL_OFF);
        #pragma unroll
        for (int e2 = 0; e2 < 4; ++e2) {
            pl[(p * 8 + e2)     * 256 + m] = plo[e2];
            pl[(p * 8 + 4 + e2) * 256 + m] = phi[e2];
        }
    }
    __syncthreads();   // S1
    if (t < 256) {
        const int m = t;
        const float* pl = (const float*)(smem + PL_OFF);
        float lg[8];
        #pragma unroll
        for (int e2 = 0; e2 < 8; ++e2) lg[e2] = gb[e2];
        #pragma unroll
        for (int pp = 0; pp < 4; ++pp)
            #pragma unroll
            for (int e2 = 0; e2 < 8; ++e2) lg[e2] += pl[(pp * 8 + e2) * 256 + m];
        int i0 = 0; float v0 = lg[0];
        #pragma unroll
        for (int e2 = 1; e2 < 8; ++e2) if (lg[e2] > v0) { v0 = lg[e2]; i0 = e2; }
        int i1 = -1; float v1 = -3.4e38f;
        #pragma unroll
        for (int e2 = 0; e2 < 8; ++e2) if (e2 != i0 && lg[e2] > v1) { v1 = lg[e2]; i1 = e2; }
        const float d  = expf(v1 - v0);
        const float q0 = 1.f / (1.f + d);
        const float q1 = d   / (1.f + d);
        ((unsigned*)(smem + SEL_OFF))[m] = (unsigned)i0 | ((unsigned)i1 << 8);
        ((float*)(smem + Q_OFF))[m * 2]     = q0;
        ((float*)(smem + Q_OFF))[m * 2 + 1] = q1;
        float cb[8];
        #pragma unroll
        for (int e2 = 0; e2 < 8; ++e2) cb[e2] = (e2 == i0) ? q0 : ((e2 == i1) ? q1 : 0.f);
        uint4 cw;
        cw.x = pk2(cb[0], cb[1]); cw.y = pk2(cb[2], cb[3]);
        cw.z = pk2(cb[4], cb[5]); cw.w = pk2(cb[6], cb[7]);
        *(uint4*)(smem + CB_OFF + m * 16) = cw;
    }
    __syncthreads();   // S2 (PL dead -> WA usable; SEL/Q/CB visible)

    // issue expert-0 weight DMA (overlaps xb preload)
    {
        const int goff = w * 1024 + lane * 16, loff = w * 1024;
        #pragma unroll
        for (int r = 0; r < 2; ++r) {
            gload16(wimg + r * 16384 + goff,          smem + WA_OFF + r * 16384 + loff);
            gload16(wimg + 262144 + r * 16384 + goff, smem + WB_OFF + r * 16384 + loff);
        }
    }

    // wave tiling: 2 M-groups (64 out-chans) x 8 N-groups (32 tokens)
    const int mg = w >> 3, ng = w & 7, col = lane & 15, kq = lane >> 4;

    int sel[2]; float cp0[2], cp1[2];
    #pragma unroll
    for (int nf = 0; nf < 2; ++nf) {
        const int tk = ng * 32 + nf * 16 + col;
        sel[nf] = ((const unsigned*)(smem + SEL_OFF))[tk];
        cp0[nf] = ((const float*)(smem + Q_OFF))[tk * 2];
        cp1[nf] = ((const float*)(smem + Q_OFF))[tk * 2 + 1];
    }
    uint4 xb[2][4];
    #pragma unroll
    for (int nf = 0; nf < 2; ++nf) {
        const int row = ng * 32 + nf * 16 + col;
        #pragma unroll
        for (int kt = 0; kt < 4; ++kt)
            xb[nf][kt] = *(const uint4*)(smem + XS_OFF + row * 256 + (((kt * 4 + kq) ^ (row & 7)) * 16));
    }
    __syncthreads();   // S3: xb safe (XS becomes H1); expert-0 weights drained

    f32x4 acc[2][4] = {};   // [m2 tok-frag][n2 o-frag]

    for (int e = 0; e < NE; ++e) {
        const float alph = ((const float*)(smem + AL_OFF))[e];
        // -------- GEMM1: h1[o][tok]; bias+PReLU, fold ce; write H1 (XS region) --------
        #pragma unroll
        for (int ml = 0; ml < 4; ++ml) {
            const int o = mg * 64 + ml * 16 + col;
            uint4 a1[4];
            #pragma unroll
            for (int kt = 0; kt < 4; ++kt)
                a1[kt] = *(const uint4*)(smem + WA_OFF + o * 256 + (((kt * 4 + kq) ^ (o & 7)) * 16));
            f32x4 h[2] = {};
            #pragma unroll
            for (int kt = 0; kt < 4; ++kt)
                #pragma unroll
                for (int nf = 0; nf < 2; ++nf)
                    h[nf] = __builtin_amdgcn_mfma_f32_16x16x32_bf16(
                        __builtin_bit_cast(bf16x8, a1[kt]),
                        __builtin_bit_cast(bf16x8, xb[nf][kt]), h[nf], 0, 0, 0);
            const int o0 = mg * 64 + ml * 16 + kq * 4;
            const f32x4 b1v = *(const f32x4*)(smem + B1_OFF + e * 512 + o0 * 4);
            #pragma unroll
            for (int nf = 0; nf < 2; ++nf) {
                const float ce = ((sel[nf] & 255) == e) ? cp0[nf]
                               : ((((sel[nf] >> 8) & 255) == e) ? cp1[nf] : 0.f);
                float hv[4];
                #pragma unroll
                for (int i = 0; i < 4; ++i) {
                    float z = h[nf][i] + b1v[i];
                    z = (z > 0.f) ? z : alph * z;
                    hv[i] = z * ce;
                }
                const int tok = ng * 32 + nf * 16 + col;
                const int g   = o0 >> 3;
                uint2 pw; pw.x = pk2(hv[0], hv[1]); pw.y = pk2(hv[2], hv[3]);
                *(uint2*)(smem + XS_OFF + tok * 256 + ((g ^ (tok & 7)) * 16) + ((o0 & 4) << 1)) = pw;
            }
        }
        __syncthreads();   // B1: H1 visible, WA free, W2[e] landed
        if (e < 7) {       // prefetch W1[e+1]; lands during GEMM2
            const int goff = w * 1024 + lane * 16, loff = w * 1024;
            const unsigned char* src = wimg + (e + 1) * 32768;
            #pragma unroll
            for (int r = 0; r < 2; ++r)
                gload16(src + r * 16384 + goff, smem + WA_OFF + r * 16384 + loff);
        }
        // -------- GEMM2 (transposed): acc[tok][o] += h1^T . W2^T --------
        #pragma unroll
        for (int kt = 0; kt < 4; ++kt) {
            uint4 hb[2], wf[4];
            #pragma unroll
            for (int m2 = 0; m2 < 2; ++m2) {
                const int tok = ng * 32 + m2 * 16 + col;
                hb[m2] = *(const uint4*)(smem + XS_OFF + tok * 256 + (((kt * 4 + kq) ^ (tok & 7)) * 16));
            }
            #pragma unroll
            for (int n2 = 0; n2 < 4; ++n2) {
                const int o2 = mg * 64 + n2 * 16 + col;
                wf[n2] = *(const uint4*)(smem + WB_OFF + o2 * 256 + (((kt * 4 + kq) ^ (o2 & 7)) * 16));
            }
            #pragma unroll
            for (int m2 = 0; m2 < 2; ++m2)
                #pragma unroll
                for (int n2 = 0; n2 < 4; ++n2)
                    acc[m2][n2] = __builtin_amdgcn_mfma_f32_16x16x32_bf16(
                        __builtin_bit_cast(bf16x8, hb[m2]),
                        __builtin_bit_cast(bf16x8, wf[n2]), acc[m2][n2], 0, 0, 0);
        }
        __syncthreads();   // B2: H1 free, WB free, W1[e+1] landed
        if (e < 7) {       // prefetch W2[e+1]; lands during next GEMM1
            const int goff = w * 1024 + lane * 16, loff = w * 1024;
            const unsigned char* src = wimg + 262144 + (e + 1) * 32768;
            #pragma unroll
            for (int r = 0; r < 2; ++r)
                gload16(src + r * 16384 + goff, smem + WB_OFF + r * 16384 + loff);
        }
    }

    // -------- bias-combine as one K=32 MFMA: acc += combine . b2 --------
    {
        const uint4 z4 = {0u, 0u, 0u, 0u};
        uint4 paf[2], pbf[4];
        #pragma unroll
        for (int m2 = 0; m2 < 2; ++m2) {
            const int tok = ng * 32 + m2 * 16 + col;
            paf[m2] = (kq == 0) ? *(const uint4*)(smem + CB_OFF + tok * 16) : z4;
        }
        #pragma unroll
        for (int n2 = 0; n2 < 4; ++n2) {
            const int o2 = mg * 64 + n2 * 16 + col;
            pbf[n2] = (kq == 0) ? *(const uint4*)(smem + B2T_OFF + o2 * 16) : z4;
        }
        #pragma unroll
        for (int m2 = 0; m2 < 2; ++m2)
            #pragma unroll
            for (int n2 = 0; n2 < 4; ++n2)
                acc[m2][n2] = __builtin_amdgcn_mfma_f32_16x16x32_bf16(
                    __builtin_bit_cast(bf16x8, paf[m2]),
                    __builtin_bit_cast(bf16x8, pbf[n2]), acc[m2][n2], 0, 0, 0);
    }

    // -------- epilogue: residual + coalesced dwordx4 stores --------
    #pragma unroll
    for (int m2 = 0; m2 < 2; ++m2) {
        const int tok0 = ng * 32 + m2 * 16 + kq * 4;
        #pragma unroll
        for (int n2 = 0; n2 < 4; ++n2) {
            const int o2 = mg * 64 + n2 * 16 + col;
            const size_t a = xbase + (size_t)o2 * SPAT + tok0;
            const f32x4 xv = *(const f32x4*)(x + a);
            f32x4 r = acc[m2][n2];
            r += xv;
            *(f32x4*)(out + a) = r;
        }
    }
}

extern "C" void kernel_launch(void* const* d_in, const int* in_sizes, int n_in,
                              void* d_out, int out_size, void* d_ws, size_t ws_size,
                              hipStream_t stream) {
    const float* x  = (const float*)d_in[0];
    const float* gw = (const float*)d_in[1];
    const float* gb = (const float*)d_in[2];
    const float* W1 = (const float*)d_in[3];
    const float* b1 = (const float*)d_in[4];
    const float* al = (const float*)d_in[5];
    const float* W2 = (const float*)d_in[6];
    const float* b2 = (const float*)d_in[7];
    (void)in_sizes; (void)n_in; (void)out_size; (void)ws_size;
    unsigned char* wimg = (unsigned char*)d_ws;   // needs 512 KiB
    float* out = (float*)d_out;

    conv_w<<<dim3(128), dim3(256), 0, stream>>>(W1, W2, wimg);
    moe_main<<<dim3(512), dim3(1024), 0, stream>>>(x, gw, gb, b1, al, b2, wimg, out);
}

// Round 4
// 144.940 us; speedup vs baseline: 1.0005x; 1.0005x over previous
//
#include <hip/hip_runtime.h>

typedef float f32x4 __attribute__((ext_vector_type(4)));
typedef __bf16 bf16x8 __attribute__((ext_vector_type(8)));

#define SPAT 65536   // t*h*w
#define CH   128
#define NE   8

// LDS layout (bytes)
#define XS_OFF   0        // 65536: X tile [256 tok][128 ch] bf16 swizzled; aliased as H1 after xb preload
#define WA_OFF   65536    // 32768: W1[e] bf16 image
#define WB_OFF   98304    // 32768: W2[e] bf16 image
#define PL_OFF   65536    // 32768: gating partials f32[4 part][8 e][256 tok]  (aliases WA, prologue only)
#define SEL_OFF  131072   // 1024 : sel u32[256]
#define Q_OFF    132096   // 2048 : q f32[256][2]
#define CB_OFF   134144   // 4096 : combine bf16[256][8]
#define B1_OFF   138240   // 4096 : b1 f32[8][128]
#define B2T_OFF  142336   // 2048 : b2^T bf16[128][8]
#define AL_OFF   144384   // 32   : alpha f32[8]
#define LDS_BYTES 144416

static __device__ __forceinline__ unsigned short f2b(float f) {
    unsigned u = __builtin_bit_cast(unsigned, f);
    unsigned r = u + 0x7FFFu + ((u >> 16) & 1u);
    return (unsigned short)(r >> 16);
}
static __device__ __forceinline__ unsigned pk2(float a, float b) {
    return (unsigned)f2b(a) | ((unsigned)f2b(b) << 16);
}

typedef const __attribute__((address_space(1))) void* as1cp;
typedef __attribute__((address_space(3))) void* as3p;
static __device__ __forceinline__ void gload16(const void* g, void* l) {
    __builtin_amdgcn_global_load_lds((as1cp)g, (as3p)l, 16, 0, 0);
}

// Pre-convert W1/W2 fp32 -> bf16 images in ws, in swizzled LDS byte order:
// image = ws + mat*262144 + e*32768 + o*256 + ((g ^ (o&7))*16), granule g = 8 ch.
__global__ void conv_w(const float* __restrict__ W1, const float* __restrict__ W2,
                       unsigned char* __restrict__ wimg) {
    const int gid = blockIdx.x * 256 + threadIdx.x;   // 32768 granules
    const int mat = gid >> 14;
    const int e   = (gid >> 11) & 7;
    const int o   = (gid >> 4) & 127;
    const int g   = gid & 15;
    const float* s = (mat ? W2 : W1) + (e * 16384 + o * 128 + g * 8);
    uint4 p;
    p.x = pk2(s[0], s[1]); p.y = pk2(s[2], s[3]);
    p.z = pk2(s[4], s[5]); p.w = pk2(s[6], s[7]);
    *(uint4*)(wimg + mat * 262144 + e * 32768 + o * 256 + ((g ^ (o & 7)) * 16)) = p;
}

// NOTE: no 2nd launch_bounds arg. A 1024-thread block already forces
// >=4 waves/SIMD co-residency -> hard VGPR cap 128. The explicit (1024,4)
// in R3 made the allocator cap at 64 VGPRs -> ~88 B/thread scratch spill
// (FETCH +40MB, WRITE +46MB). Let it use the full 128.
__global__ __launch_bounds__(1024)
void moe_main(const float* __restrict__ x,  const float* __restrict__ gw,
              const float* __restrict__ gb, const float* __restrict__ b1,
              const float* __restrict__ alpha, const float* __restrict__ b2,
              const unsigned char* __restrict__ wimg, float* __restrict__ out)
{
    __shared__ __align__(16) unsigned char smem[LDS_BYTES];
    const int t = threadIdx.x, lane = t & 63, w = t >> 6, blk = blockIdx.x;
    const size_t xbase = (size_t)(blk >> 8) * (size_t)(CH * SPAT) + (size_t)((blk & 255) << 8);

    // stage small params (disjoint regions, before S1)
    if (t < 256) ((f32x4*)(smem + B1_OFF))[t] = ((const f32x4*)b1)[t];
    else if (t >= 256 && t < 384) {
        const int j = t - 256;
        uint4 p;
        p.x = pk2(b2[0 * 128 + j], b2[1 * 128 + j]);
        p.y = pk2(b2[2 * 128 + j], b2[3 * 128 + j]);
        p.z = pk2(b2[4 * 128 + j], b2[5 * 128 + j]);
        p.w = pk2(b2[6 * 128 + j], b2[7 * 128 + j]);
        *(uint4*)(smem + B2T_OFF + j * 16) = p;
    } else if (t >= 384 && t < 392) {
        ((float*)(smem + AL_OFF))[t - 384] = alpha[t - 384];
    }

    // ---- stage X (fp32->bf16, swizzled) + fp32 gating partials (4 parts x 32ch) ----
    {
        const int m = t & 255, p = t >> 8;     // token, channel-part
        f32x4 plo = {0.f,0.f,0.f,0.f}, phi = {0.f,0.f,0.f,0.f};
        #pragma unroll
        for (int cc = 0; cc < 4; ++cc) {
            const int c0 = p * 32 + cc * 8;
            float v[8];
            #pragma unroll
            for (int j = 0; j < 8; ++j) v[j] = x[xbase + (size_t)(c0 + j) * SPAT + m];
            #pragma unroll
            for (int j = 0; j < 8; ++j) {
                const f32x4 g0 = *(const f32x4*)(gw + (c0 + j) * NE);
                const f32x4 g1 = *(const f32x4*)(gw + (c0 + j) * NE + 4);
                plo += v[j] * g0; phi += v[j] * g1;
            }
            uint4 pkv;
            pkv.x = pk2(v[0], v[1]); pkv.y = pk2(v[2], v[3]);
            pkv.z = pk2(v[4], v[5]); pkv.w = pk2(v[6], v[7]);
            const int g = p * 4 + cc;
            *(uint4*)(smem + XS_OFF + m * 256 + ((g ^ (m & 7)) * 16)) = pkv;
        }
        // PL[part][e][tok] — stride-1 in tok => conflict-free
        float* pl = (float*)(smem + PL_OFF);
        #pragma unroll
        for (int e2 = 0; e2 < 4; ++e2) {
            pl[(p * 8 + e2)     * 256 + m] = plo[e2];
            pl[(p * 8 + 4 + e2) * 256 + m] = phi[e2];
        }
    }
    __syncthreads();   // S1
    if (t < 256) {
        const int m = t;
        const float* pl = (const float*)(smem + PL_OFF);
        float lg[8];
        #pragma unroll
        for (int e2 = 0; e2 < 8; ++e2) lg[e2] = gb[e2];
        #pragma unroll
        for (int pp = 0; pp < 4; ++pp)
            #pragma unroll
            for (int e2 = 0; e2 < 8; ++e2) lg[e2] += pl[(pp * 8 + e2) * 256 + m];
        int i0 = 0; float v0 = lg[0];
        #pragma unroll
        for (int e2 = 1; e2 < 8; ++e2) if (lg[e2] > v0) { v0 = lg[e2]; i0 = e2; }
        int i1 = -1; float v1 = -3.4e38f;
        #pragma unroll
        for (int e2 = 0; e2 < 8; ++e2) if (e2 != i0 && lg[e2] > v1) { v1 = lg[e2]; i1 = e2; }
        const float d  = expf(v1 - v0);
        const float q0 = 1.f / (1.f + d);
        const float q1 = d   / (1.f + d);
        ((unsigned*)(smem + SEL_OFF))[m] = (unsigned)i0 | ((unsigned)i1 << 8);
        ((float*)(smem + Q_OFF))[m * 2]     = q0;
        ((float*)(smem + Q_OFF))[m * 2 + 1] = q1;
        float cb[8];
        #pragma unroll
        for (int e2 = 0; e2 < 8; ++e2) cb[e2] = (e2 == i0) ? q0 : ((e2 == i1) ? q1 : 0.f);
        uint4 cw;
        cw.x = pk2(cb[0], cb[1]); cw.y = pk2(cb[2], cb[3]);
        cw.z = pk2(cb[4], cb[5]); cw.w = pk2(cb[6], cb[7]);
        *(uint4*)(smem + CB_OFF + m * 16) = cw;
    }
    __syncthreads();   // S2 (PL dead -> WA usable; SEL/Q/CB visible)

    // issue expert-0 weight DMA (overlaps xb preload)
    {
        const int goff = w * 1024 + lane * 16, loff = w * 1024;
        #pragma unroll
        for (int r = 0; r < 2; ++r) {
            gload16(wimg + r * 16384 + goff,          smem + WA_OFF + r * 16384 + loff);
            gload16(wimg + 262144 + r * 16384 + goff, smem + WB_OFF + r * 16384 + loff);
        }
    }

    // wave tiling: 2 M-groups (64 out-chans) x 8 N-groups (32 tokens)
    const int mg = w >> 3, ng = w & 7, col = lane & 15, kq = lane >> 4;

    int sel[2]; float cp0[2], cp1[2];
    #pragma unroll
    for (int nf = 0; nf < 2; ++nf) {
        const int tk = ng * 32 + nf * 16 + col;
        sel[nf] = ((const unsigned*)(smem + SEL_OFF))[tk];
        cp0[nf] = ((const float*)(smem + Q_OFF))[tk * 2];
        cp1[nf] = ((const float*)(smem + Q_OFF))[tk * 2 + 1];
    }
    uint4 xb[2][4];
    #pragma unroll
    for (int nf = 0; nf < 2; ++nf) {
        const int row = ng * 32 + nf * 16 + col;
        #pragma unroll
        for (int kt = 0; kt < 4; ++kt)
            xb[nf][kt] = *(const uint4*)(smem + XS_OFF + row * 256 + (((kt * 4 + kq) ^ (row & 7)) * 16));
    }
    __syncthreads();   // S3: xb safe (XS becomes H1); expert-0 weights drained

    f32x4 acc[2][4] = {};   // [m2 tok-frag][n2 o-frag]

    for (int e = 0; e < NE; ++e) {
        const float alph = ((const float*)(smem + AL_OFF))[e];
        // -------- GEMM1: h1[o][tok]; bias+PReLU, fold ce; write H1 (XS region) --------
        #pragma unroll
        for (int ml = 0; ml < 4; ++ml) {
            const int o = mg * 64 + ml * 16 + col;
            uint4 a1[4];
            #pragma unroll
            for (int kt = 0; kt < 4; ++kt)
                a1[kt] = *(const uint4*)(smem + WA_OFF + o * 256 + (((kt * 4 + kq) ^ (o & 7)) * 16));
            f32x4 h[2] = {};
            #pragma unroll
            for (int kt = 0; kt < 4; ++kt)
                #pragma unroll
                for (int nf = 0; nf < 2; ++nf)
                    h[nf] = __builtin_amdgcn_mfma_f32_16x16x32_bf16(
                        __builtin_bit_cast(bf16x8, a1[kt]),
                        __builtin_bit_cast(bf16x8, xb[nf][kt]), h[nf], 0, 0, 0);
            const int o0 = mg * 64 + ml * 16 + kq * 4;
            const f32x4 b1v = *(const f32x4*)(smem + B1_OFF + e * 512 + o0 * 4);
            #pragma unroll
            for (int nf = 0; nf < 2; ++nf) {
                const float ce = ((sel[nf] & 255) == e) ? cp0[nf]
                               : ((((sel[nf] >> 8) & 255) == e) ? cp1[nf] : 0.f);
                float hv[4];
                #pragma unroll
                for (int i = 0; i < 4; ++i) {
                    float z = h[nf][i] + b1v[i];
                    z = (z > 0.f) ? z : alph * z;
                    hv[i] = z * ce;
                }
                const int tok = ng * 32 + nf * 16 + col;
                const int g   = o0 >> 3;
                uint2 pw; pw.x = pk2(hv[0], hv[1]); pw.y = pk2(hv[2], hv[3]);
                *(uint2*)(smem + XS_OFF + tok * 256 + ((g ^ (tok & 7)) * 16) + ((o0 & 4) << 1)) = pw;
            }
        }
        __syncthreads();   // B1: H1 visible, WA free, W2[e] landed
        if (e < 7) {       // prefetch W1[e+1]; lands during GEMM2
            const int goff = w * 1024 + lane * 16, loff = w * 1024;
            const unsigned char* src = wimg + (e + 1) * 32768;
            #pragma unroll
            for (int r = 0; r < 2; ++r)
                gload16(src + r * 16384 + goff, smem + WA_OFF + r * 16384 + loff);
        }
        // -------- GEMM2 (transposed): acc[tok][o] += h1^T . W2^T --------
        #pragma unroll
        for (int kt = 0; kt < 4; ++kt) {
            uint4 hb[2], wf[4];
            #pragma unroll
            for (int m2 = 0; m2 < 2; ++m2) {
                const int tok = ng * 32 + m2 * 16 + col;
                hb[m2] = *(const uint4*)(smem + XS_OFF + tok * 256 + (((kt * 4 + kq) ^ (tok & 7)) * 16));
            }
            #pragma unroll
            for (int n2 = 0; n2 < 4; ++n2) {
                const int o2 = mg * 64 + n2 * 16 + col;
                wf[n2] = *(const uint4*)(smem + WB_OFF + o2 * 256 + (((kt * 4 + kq) ^ (o2 & 7)) * 16));
            }
            #pragma unroll
            for (int m2 = 0; m2 < 2; ++m2)
                #pragma unroll
                for (int n2 = 0; n2 < 4; ++n2)
                    acc[m2][n2] = __builtin_amdgcn_mfma_f32_16x16x32_bf16(
                        __builtin_bit_cast(bf16x8, hb[m2]),
                        __builtin_bit_cast(bf16x8, wf[n2]), acc[m2][n2], 0, 0, 0);
        }
        __syncthreads();   // B2: H1 free, WB free, W1[e+1] landed
        if (e < 7) {       // prefetch W2[e+1]; lands during next GEMM1
            const int goff = w * 1024 + lane * 16, loff = w * 1024;
            const unsigned char* src = wimg + 262144 + (e + 1) * 32768;
            #pragma unroll
            for (int r = 0; r < 2; ++r)
                gload16(src + r * 16384 + goff, smem + WB_OFF + r * 16384 + loff);
        }
    }

    // -------- bias-combine as one K=32 MFMA: acc += combine . b2 --------
    {
        const uint4 z4 = {0u, 0u, 0u, 0u};
        uint4 paf[2], pbf[4];
        #pragma unroll
        for (int m2 = 0; m2 < 2; ++m2) {
            const int tok = ng * 32 + m2 * 16 + col;
            paf[m2] = (kq == 0) ? *(const uint4*)(smem + CB_OFF + tok * 16) : z4;
        }
        #pragma unroll
        for (int n2 = 0; n2 < 4; ++n2) {
            const int o2 = mg * 64 + n2 * 16 + col;
            pbf[n2] = (kq == 0) ? *(const uint4*)(smem + B2T_OFF + o2 * 16) : z4;
        }
        #pragma unroll
        for (int m2 = 0; m2 < 2; ++m2)
            #pragma unroll
            for (int n2 = 0; n2 < 4; ++n2)
                acc[m2][n2] = __builtin_amdgcn_mfma_f32_16x16x32_bf16(
                    __builtin_bit_cast(bf16x8, paf[m2]),
                    __builtin_bit_cast(bf16x8, pbf[n2]), acc[m2][n2], 0, 0, 0);
    }

    // -------- epilogue: residual + coalesced dwordx4 stores --------
    #pragma unroll
    for (int m2 = 0; m2 < 2; ++m2) {
        const int tok0 = ng * 32 + m2 * 16 + kq * 4;
        #pragma unroll
        for (int n2 = 0; n2 < 4; ++n2) {
            const int o2 = mg * 64 + n2 * 16 + col;
            const size_t a = xbase + (size_t)o2 * SPAT + tok0;
            const f32x4 xv = *(const f32x4*)(x + a);
            f32x4 r = acc[m2][n2];
            r += xv;
            *(f32x4*)(out + a) = r;
        }
    }
}

extern "C" void kernel_launch(void* const* d_in, const int* in_sizes, int n_in,
                              void* d_out, int out_size, void* d_ws, size_t ws_size,
                              hipStream_t stream) {
    const float* x  = (const float*)d_in[0];
    const float* gw = (const float*)d_in[1];
    const float* gb = (const float*)d_in[2];
    const float* W1 = (const float*)d_in[3];
    const float* b1 = (const float*)d_in[4];
    const float* al = (const float*)d_in[5];
    const float* W2 = (const float*)d_in[6];
    const float* b2 = (const float*)d_in[7];
    (void)in_sizes; (void)n_in; (void)out_size; (void)ws_size;
    unsigned char* wimg = (unsigned char*)d_ws;   // needs 512 KiB
    float* out = (float*)d_out;

    conv_w<<<dim3(128), dim3(256), 0, stream>>>(W1, W2, wimg);
    moe_main<<<dim3(512), dim3(1024), 0, stream>>>(x, gw, gb, b1, al, b2, wimg, out);
}